// Round 14
// baseline (251.814 us; speedup 1.0000x reference)
//
#include <hip/hip_runtime.h>

typedef _Float16 f16;
typedef _Float16 half8 __attribute__((ext_vector_type(8)));
typedef _Float16 half4v __attribute__((ext_vector_type(4)));
typedef __fp16 fp16x2 __attribute__((ext_vector_type(2)));
typedef float f32x4 __attribute__((ext_vector_type(4)));
typedef float f32x16 __attribute__((ext_vector_type(16)));
typedef unsigned uint4v __attribute__((ext_vector_type(4)));

#define MFMA16(a,b,c) __builtin_amdgcn_mfma_f32_16x16x32_f16((a),(b),(c),0,0,0)
#define MFMA32(a,b,c) __builtin_amdgcn_mfma_f32_32x32x16_f16((a),(b),(c),0,0,0)

__device__ __forceinline__ void gload_lds16(const f16* g, f16* l) {
    __builtin_amdgcn_global_load_lds(
        (const __attribute__((address_space(1))) unsigned int*)g,
        (__attribute__((address_space(3))) unsigned int*)l, 16, 0, 0);
}

__device__ __forceinline__ void plswap(unsigned &a, unsigned &b) {
    asm volatile("v_permlane32_swap_b32 %0, %1" : "+v"(a), "+v"(b));
}

__device__ __forceinline__ unsigned pk2(float a, float b) {
    return __builtin_bit_cast(unsigned, __builtin_amdgcn_cvt_pkrtz(a, b));
}

// lane <-> lane^32 exchange via full-rate permlane (not ds_bpermute)
__device__ __forceinline__ float xswap32(float x, int hi) {
    unsigned a = __builtin_bit_cast(unsigned, x), b = a;
    asm volatile("v_permlane32_swap_b32 %0, %1" : "+v"(a), "+v"(b));
    return __builtin_bit_cast(float, hi ? a : b);
}

// ---------------- cast fp32 -> fp16 (vectorized) ----------------
__global__ void cast_f32_to_f16(const float* __restrict__ in, f16* __restrict__ out, int n4) {
    int i = blockIdx.x * blockDim.x + threadIdx.x;
    if (i < n4) {
        float4 v = ((const float4*)in)[i];
        half4v h;
        h.x = (f16)v.x; h.y = (f16)v.y; h.z = (f16)v.z; h.w = (f16)v.w;
        ((half4v*)out)[i] = h;
    }
}

// ---------------- transpose + cast: in[K][N] fp32 -> out[N][K] fp16 ----------------
__global__ void transpose_cast(const float* __restrict__ in, f16* __restrict__ out, int K, int N) {
    __shared__ f16 tile[32][33];
    int n0 = blockIdx.x * 32, k0 = blockIdx.y * 32;
    int tx = threadIdx.x & 31, ty = threadIdx.x >> 5;   // 256 threads = 32x8
    for (int r = ty; r < 32; r += 8)
        tile[r][tx] = (f16)in[(size_t)(k0 + r) * N + (n0 + tx)];
    __syncthreads();
    for (int r = ty; r < 32; r += 8)
        out[(size_t)(n0 + r) * K + (k0 + tx)] = tile[tx][r];
}

// ---------------- GEMM: C[M][N] = A[M][768] * Bt[N][768]^T ----------------
template<int MODE>
__global__ __launch_bounds__(256, 3)
void gemm_bt(const f16* __restrict__ A, const f16* __restrict__ Bt,
             f16* __restrict__ qbuf, f16* __restrict__ kbuf, f16* __restrict__ vtbuf,
             float* __restrict__ out, const float* __restrict__ bias)
{
    constexpr int K = 768;
    constexpr int NX = (MODE == 0) ? 18 : 6;   // n-tiles
    constexpr int NWG = NX * 64;
    __shared__ __align__(16) char smem[49152];
    f16* As = (f16*)smem;              // [3][128*32]
    f16* Bs = (f16*)(smem + 24576);    // [3][128*32]
    const int tid  = threadIdx.x;
    const int lane = tid & 63, wave = tid >> 6;
    const int wm = wave >> 1, wn = wave & 1;          // 2x2 waves, 64x64 each
    const int l15 = lane & 15, l4 = lane >> 4;

    const int bid = blockIdx.x;
    const int swz = (bid & 7) * (NWG / 8) + (bid >> 3);
    const int m0 = (swz / NX) * 128, n0 = (swz % NX) * 128;

    const int srow  = lane >> 2;
    const int sslot = lane & 3;

    f32x4 acc[4][4] = {};

    #define GSTAGE(buf, kt) do {                                                     \
        _Pragma("unroll")                                                            \
        for (int i = 0; i < 2; ++i) {                                                \
            int rbase = i * 64 + wave * 16;                                          \
            int row = rbase + srow;                                                  \
            gload_lds16(A  + (size_t)(m0 + row) * K + (kt) + sslot * 8, &As[(buf) * 4096 + rbase * 32]); \
            gload_lds16(Bt + (size_t)(n0 + row) * K + (kt) + sslot * 8, &Bs[(buf) * 4096 + rbase * 32]); \
        }                                                                            \
    } while (0)

    GSTAGE(0, 0);
    GSTAGE(1, 32);

    int cur = 0;
    for (int t = 0; t < 24; ++t) {
        if (t < 23) asm volatile("s_waitcnt vmcnt(4)" ::: "memory");
        else        asm volatile("s_waitcnt vmcnt(0)" ::: "memory");
        __builtin_amdgcn_s_barrier();
        if (t < 22) {
            int nb = cur + 2; if (nb >= 3) nb -= 3;
            GSTAGE(nb, (t + 2) * 32);
        }
        half8 af[4], bf[4];
        #pragma unroll
        for (int mi = 0; mi < 4; mi++) af[mi] = *(const half8*)&As[cur*4096 + (wm*64 + mi*16 + l15) * 32 + l4*8];
        #pragma unroll
        for (int ni = 0; ni < 4; ni++) bf[ni] = *(const half8*)&Bs[cur*4096 + (wn*64 + ni*16 + l15) * 32 + l4*8];
        #pragma unroll
        for (int mi = 0; mi < 4; mi++)
            #pragma unroll
            for (int ni = 0; ni < 4; ni++)
                acc[mi][ni] = MFMA16(af[mi], bf[ni], acc[mi][ni]);
        if (++cur >= 3) cur = 0;
    }
    #undef GSTAGE

    if (MODE == 0) {
        __syncthreads();
        f16* sC = (f16*)smem;          // [128][136]
        const int t3 = n0 / 768;
        const int bb = m0 >> 10;
        const int mo = m0 & 1023;
        const int h0 = (n0 - t3 * 768) >> 6;

        if (t3 < 2) {
            #pragma unroll
            for (int mi = 0; mi < 4; mi++)
                #pragma unroll
                for (int ni = 0; ni < 4; ni++)
                    #pragma unroll
                    for (int r = 0; r < 4; r++) {
                        int row = wm*64 + mi*16 + l4*4 + r;
                        int col = wn*64 + ni*16 + l15;
                        sC[row * 136 + col] = (f16)acc[mi][ni][r];
                    }
            __syncthreads();
            f16* outb = (t3 == 0) ? qbuf : kbuf;
            #pragma unroll
            for (int hc = 0; hc < 2; hc++) {
                f16* base = outb + ((size_t)(bb * 12 + h0 + hc) * 1024 + mo) * 64;
                #pragma unroll
                for (int i = 0; i < 4; i++) {
                    int row = wave * 32 + i * 8 + (lane >> 3);
                    int cc  = (lane & 7) * 8;
                    half8 v = *(const half8*)&sC[row * 136 + hc * 64 + cc];
                    *(half8*)(base + row * 64 + cc) = v;
                }
            }
        } else {
            #pragma unroll
            for (int mi = 0; mi < 4; mi++)
                #pragma unroll
                for (int ni = 0; ni < 4; ni++) {
                    int row0 = wm*64 + mi*16 + l4*4;
                    int col  = wn*64 + ni*16 + l15;
                    half4v pk;
                    #pragma unroll
                    for (int r = 0; r < 4; r++) pk[r] = (f16)acc[mi][ni][r];
                    *(half4v*)&sC[col * 136 + row0] = pk;
                }
            __syncthreads();
            #pragma unroll
            for (int i = 0; i < 8; i++) {
                int col = wave * 32 + i * 4 + (lane >> 4);
                int rc  = (lane & 15) * 8;
                half8 v = *(const half8*)&sC[col * 136 + rc];
                int head = h0 + (col >> 6), dd = col & 63;
                *(half8*)(vtbuf + ((size_t)(bb * 12 + head) * 64 + dd) * 1024 + mo + rc) = v;
            }
        }
    } else {
        #pragma unroll
        for (int mi = 0; mi < 4; mi++)
            #pragma unroll
            for (int ni = 0; ni < 4; ni++)
                #pragma unroll
                for (int r = 0; r < 4; r++) {
                    int gm = m0 + wm*64 + mi*16 + l4*4 + r;
                    int gn = n0 + wn*64 + ni*16 + l15;
                    out[(size_t)gm * 768 + gn] = acc[mi][ni][r] + bias[gn];
                }
    }
}

// ---------------- flash attention (ablation template) ----------------
// V=0 real | V=1 nomax | V=2 noexp | V=3 skeleton (STAGE+QK+PV only)
template<int V>
__global__ __launch_bounds__(256, 4)
void attn_kernel(const f16* __restrict__ qbuf, const f16* __restrict__ kbuf,
                 const f16* __restrict__ vtbuf, f16* __restrict__ obuf)
{
    __shared__ __align__(16) f16 Ks[2][4096];
    __shared__ __align__(16) f16 Vs[2][4096];
    const int tid = threadIdx.x;
    const int lane = tid & 63, wave = tid >> 6;
    const int bh = blockIdx.x;              // 0..95
    const int b = bh / 12, h = bh % 12;
    const int q0 = blockIdx.y * 128 + wave * 32;
    const int l31 = lane & 31, hi = lane >> 5;
    const int sw0 = (l31 & 7) << 4;

    const f16* Q  = qbuf  + (size_t)bh * 65536;
    const f16* Kp = kbuf  + (size_t)bh * 65536;
    const f16* Vt = vtbuf + (size_t)bh * 65536;

    const f16 slh = (f16)(0.125f * 1.44269504089f);
    half8 aq[4];
    #pragma unroll
    for (int c = 0; c < 4; c++) {
        aq[c] = *(const half8*)&Q[(size_t)(q0 + l31) * 64 + c * 16 + hi * 8];
        #pragma unroll
        for (int j = 0; j < 8; j++) aq[c][j] *= slh;
    }

    const int srow8 = lane >> 3;
    const int c16   = (lane & 7) ^ srow8;

    f32x16 o0 = {}, o1 = {};
    float lrq = (V == 3) ? 1.f : 0.f, mrq = 0.f;

    #define STAGE(buf, kv) do {                                                     \
        _Pragma("unroll")                                                           \
        for (int i = 0; i < 2; ++i) {                                               \
            int rbase = wave * 16 + i * 8;                                          \
            int rl = rbase + srow8;                                                 \
            gload_lds16(Kp + (size_t)((kv) + rl) * 64 + c16 * 8, &Ks[buf][rbase * 64]); \
            gload_lds16(Vt + (size_t)rl * 1024 + (kv) + c16 * 8, &Vs[buf][rbase * 64]); \
        }                                                                           \
    } while (0)

    STAGE(0, 0);
    __syncthreads();

    for (int t = 0; t < 16; ++t) {
        const int cur = t & 1;
        if (t < 15) STAGE(cur ^ 1, (t + 1) * 64);

        const char* Kb = (const char*)&Ks[cur][0];
        const char* Vb = (const char*)&Vs[cur][0];

        // swapped QK (32x32x16): st = S^T[key][q] - mrq, log2 domain
        f32x16 st0, st1;
        #pragma unroll
        for (int j = 0; j < 16; j++) { st0[j] = -mrq; st1[j] = -mrq; }
        __builtin_amdgcn_s_setprio(1);
        #pragma unroll
        for (int c = 0; c < 4; c++) {
            int koff = (c * 32 + hi * 16) ^ sw0;
            half8 k0 = *(const half8*)(Kb + l31 * 128 + koff);
            half8 k1 = *(const half8*)(Kb + (32 + l31) * 128 + koff);
            st0 = MFMA32(k0, aq[c], st0);
            st1 = MFMA32(k1, aq[c], st1);
        }
        __builtin_amdgcn_s_setprio(0);

        if constexpr (V == 3) {
            // skeleton: keep QK live via cheap fold; PV fed from aq
            #pragma unroll
            for (int j = 0; j < 16; j++) { o0[j] += st0[j]; o1[j] += st1[j]; }
            __builtin_amdgcn_s_setprio(1);
            #pragma unroll
            for (int kc = 0; kc < 4; kc++) {
                int koff = (kc * 32 + hi * 16) ^ sw0;
                half8 v0 = *(const half8*)(Vb + l31 * 128 + koff);
                half8 v1 = *(const half8*)(Vb + (32 + l31) * 128 + koff);
                o0 = MFMA32(aq[kc], v0, o0);
                o1 = MFMA32(aq[kc], v1, o1);
            }
            __builtin_amdgcn_s_setprio(0);
            __syncthreads();
            continue;
        }

        if constexpr (V == 0 || V == 2) {
            // row max: depth-5 balanced tree
            float m16;
            {
                float p0 = fmaxf(fmaxf(st0[0],  st0[1]),  fmaxf(st0[2],  st0[3]));
                float p1 = fmaxf(fmaxf(st0[4],  st0[5]),  fmaxf(st0[6],  st0[7]));
                float p2 = fmaxf(fmaxf(st0[8],  st0[9]),  fmaxf(st0[10], st0[11]));
                float p3 = fmaxf(fmaxf(st0[12], st0[13]), fmaxf(st0[14], st0[15]));
                float r0 = fmaxf(fmaxf(st1[0],  st1[1]),  fmaxf(st1[2],  st1[3]));
                float r1 = fmaxf(fmaxf(st1[4],  st1[5]),  fmaxf(st1[6],  st1[7]));
                float r2 = fmaxf(fmaxf(st1[8],  st1[9]),  fmaxf(st1[10], st1[11]));
                float r3 = fmaxf(fmaxf(st1[12], st1[13]), fmaxf(st1[14], st1[15]));
                m16 = fmaxf(fmaxf(fmaxf(p0, p1), fmaxf(p2, p3)),
                            fmaxf(fmaxf(r0, r1), fmaxf(r2, r3)));
            }
            m16 = fmaxf(m16, xswap32(m16, hi));

            if (!__all(m16 <= 11.0f)) {
                float d = fmaxf(m16, 0.f);
                float alpha = exp2f(-d);
                mrq += d;
                #pragma unroll
                for (int j = 0; j < 16; j++) { st0[j] -= d; st1[j] -= d; }
                lrq *= alpha;
                #pragma unroll
                for (int reg = 0; reg < 16; reg++) {
                    float a = __shfl(alpha, (reg & 3) + 8 * (reg >> 2) + 4 * hi);
                    o0[reg] *= a; o1[reg] *= a;
                }
            }
        }

        // P path: exp2 (identity for V2) -> pack -> permlane -> PV A-frags
        float rs = 0.f;
        half8 pa[4];
        #pragma unroll
        for (int tile = 0; tile < 2; tile++) {
            const f32x16& sv = tile ? st1 : st0;
            #pragma unroll
            for (int half16 = 0; half16 < 2; half16++) {
                int rb = half16 * 8;
                unsigned A1, B1, A2, B2;
                {
                    float e0 = (V == 2) ? sv[rb+0] : exp2f(sv[rb+0]);
                    float e1 = (V == 2) ? sv[rb+1] : exp2f(sv[rb+1]);
                    float e4 = (V == 2) ? sv[rb+4] : exp2f(sv[rb+4]);
                    float e5 = (V == 2) ? sv[rb+5] : exp2f(sv[rb+5]);
                    rs += (e0 + e1) + (e4 + e5);
                    A1 = pk2(e0, e1); B1 = pk2(e4, e5);
                    plswap(A1, B1);
                }
                {
                    float e2 = (V == 2) ? sv[rb+2] : exp2f(sv[rb+2]);
                    float e3 = (V == 2) ? sv[rb+3] : exp2f(sv[rb+3]);
                    float e6 = (V == 2) ? sv[rb+6] : exp2f(sv[rb+6]);
                    float e7 = (V == 2) ? sv[rb+7] : exp2f(sv[rb+7]);
                    rs += (e2 + e3) + (e6 + e7);
                    A2 = pk2(e2, e3); B2 = pk2(e6, e7);
                    plswap(A2, B2);
                }
                uint4v w = {A1, A2, B1, B2};
                pa[tile * 2 + half16] = __builtin_bit_cast(half8, w);
            }
        }
        rs += xswap32(rs, hi);
        lrq += rs;

        // PV (32x32x16)
        __builtin_amdgcn_s_setprio(1);
        #pragma unroll
        for (int kc = 0; kc < 4; kc++) {
            int koff = (kc * 32 + hi * 16) ^ sw0;
            half8 v0 = *(const half8*)(Vb + l31 * 128 + koff);
            half8 v1 = *(const half8*)(Vb + (32 + l31) * 128 + koff);
            o0 = MFMA32(pa[kc], v0, o0);
            o1 = MFMA32(pa[kc], v1, o1);
        }
        __builtin_amdgcn_s_setprio(0);

        __syncthreads();
    }
    #undef STAGE

    float rq = 1.0f / lrq;
    f16* Op = obuf + (size_t)b * 1024 * 768 + h * 64;
    #pragma unroll
    for (int reg = 0; reg < 16; reg++) {
        int qrow = (reg & 3) + 8 * (reg >> 2) + 4 * hi;
        float inv = __shfl(rq, qrow);
        size_t base = (size_t)(q0 + qrow) * 768;
        Op[base + l31]      = (f16)(o0[reg] * inv);
        Op[base + 32 + l31] = (f16)(o1[reg] * inv);
    }
}

extern "C" void kernel_launch(void* const* d_in, const int* in_sizes, int n_in,
                              void* d_out, int out_size, void* d_ws, size_t ws_size,
                              hipStream_t stream) {
    const float* x      = (const float*)d_in[0];
    const float* w_qkv  = (const float*)d_in[1];
    const float* w_proj = (const float*)d_in[2];
    const float* b_proj = (const float*)d_in[3];
    float* out = (float*)d_out;
    char* ws = (char*)d_ws;

    f16* x_h      = (f16*)(ws + 0);
    f16* w_qkv_t  = (f16*)(ws + 12582912);
    f16* w_proj_t = (f16*)(ws + 16121856);
    f16* qb       = (f16*)(ws + 17301504);
    f16* kb       = (f16*)(ws + 29884416);
    f16* vtb      = (f16*)(ws + 42467328);
    f16* ob       = (f16*)(ws + 55050240);

    cast_f32_to_f16<<<dim3(6144), dim3(256), 0, stream>>>(x, x_h, 6291456 / 4);
    transpose_cast<<<dim3(2304 / 32, 768 / 32), dim3(256), 0, stream>>>(w_qkv, w_qkv_t, 768, 2304);
    transpose_cast<<<dim3(768 / 32, 768 / 32), dim3(256), 0, stream>>>(w_proj, w_proj_t, 768, 768);
    gemm_bt<0><<<dim3(18 * 64), dim3(256), 0, stream>>>(
        x_h, w_qkv_t, qb, kb, vtb, nullptr, nullptr);
    // --- ablation probes (write garbage to ob; fully overwritten by the real V0 below) ---
    attn_kernel<3><<<dim3(96, 8), dim3(256), 0, stream>>>(qb, kb, vtb, ob);  // skeleton
    attn_kernel<2><<<dim3(96, 8), dim3(256), 0, stream>>>(qb, kb, vtb, ob);  // noexp
    attn_kernel<1><<<dim3(96, 8), dim3(256), 0, stream>>>(qb, kb, vtb, ob);  // nomax
    // --- real ---
    attn_kernel<0><<<dim3(96, 8), dim3(256), 0, stream>>>(qb, kb, vtb, ob);
    gemm_bt<1><<<dim3(6 * 64), dim3(256), 0, stream>>>(
        ob, w_proj_t, nullptr, nullptr, nullptr, out, b_proj);
}

// Round 15
// 156.546 us; speedup vs baseline: 1.6086x; 1.6086x over previous
//
#include <hip/hip_runtime.h>

typedef _Float16 f16;
typedef _Float16 half8 __attribute__((ext_vector_type(8)));
typedef _Float16 half4v __attribute__((ext_vector_type(4)));
typedef __fp16 fp16x2 __attribute__((ext_vector_type(2)));
typedef float f32x4 __attribute__((ext_vector_type(4)));
typedef float f32x16 __attribute__((ext_vector_type(16)));
typedef unsigned uint4v __attribute__((ext_vector_type(4)));

#define MFMA16(a,b,c) __builtin_amdgcn_mfma_f32_16x16x32_f16((a),(b),(c),0,0,0)
#define MFMA32(a,b,c) __builtin_amdgcn_mfma_f32_32x32x16_f16((a),(b),(c),0,0,0)

__device__ __forceinline__ void gload_lds16(const f16* g, f16* l) {
    __builtin_amdgcn_global_load_lds(
        (const __attribute__((address_space(1))) unsigned int*)g,
        (__attribute__((address_space(3))) unsigned int*)l, 16, 0, 0);
}

__device__ __forceinline__ void plswap(unsigned &a, unsigned &b) {
    asm volatile("v_permlane32_swap_b32 %0, %1" : "+v"(a), "+v"(b));
}

__device__ __forceinline__ unsigned pk2(float a, float b) {
    return __builtin_bit_cast(unsigned, __builtin_amdgcn_cvt_pkrtz(a, b));
}

// lane <-> lane^32 exchange via full-rate permlane (not ds_bpermute)
__device__ __forceinline__ float xswap32(float x, int hi) {
    unsigned a = __builtin_bit_cast(unsigned, x), b = a;
    asm volatile("v_permlane32_swap_b32 %0, %1" : "+v"(a), "+v"(b));
    return __builtin_bit_cast(float, hi ? a : b);
}

// ---------------- cast fp32 -> fp16 (vectorized) ----------------
__global__ void cast_f32_to_f16(const float* __restrict__ in, f16* __restrict__ out, int n4) {
    int i = blockIdx.x * blockDim.x + threadIdx.x;
    if (i < n4) {
        float4 v = ((const float4*)in)[i];
        half4v h;
        h.x = (f16)v.x; h.y = (f16)v.y; h.z = (f16)v.z; h.w = (f16)v.w;
        ((half4v*)out)[i] = h;
    }
}

// ---------------- transpose + cast: in[K][N] fp32 -> out[N][K] fp16 ----------------
__global__ void transpose_cast(const float* __restrict__ in, f16* __restrict__ out, int K, int N) {
    __shared__ f16 tile[32][33];
    int n0 = blockIdx.x * 32, k0 = blockIdx.y * 32;
    int tx = threadIdx.x & 31, ty = threadIdx.x >> 5;   // 256 threads = 32x8
    for (int r = ty; r < 32; r += 8)
        tile[r][tx] = (f16)in[(size_t)(k0 + r) * N + (n0 + tx)];
    __syncthreads();
    for (int r = ty; r < 32; r += 8)
        out[(size_t)(n0 + r) * K + (k0 + tx)] = tile[tx][r];
}

// ---------------- GEMM: C[M][N] = A[M][768] * Bt[N][768]^T ----------------
template<int MODE>
__global__ __launch_bounds__(256, 3)
void gemm_bt(const f16* __restrict__ A, const f16* __restrict__ Bt,
             f16* __restrict__ qbuf, f16* __restrict__ kbuf, f16* __restrict__ vtbuf,
             float* __restrict__ out, const float* __restrict__ bias)
{
    constexpr int K = 768;
    constexpr int NX = (MODE == 0) ? 18 : 6;   // n-tiles
    constexpr int NWG = NX * 64;
    __shared__ __align__(16) char smem[49152];
    f16* As = (f16*)smem;              // [3][128*32]
    f16* Bs = (f16*)(smem + 24576);    // [3][128*32]
    const int tid  = threadIdx.x;
    const int lane = tid & 63, wave = tid >> 6;
    const int wm = wave >> 1, wn = wave & 1;          // 2x2 waves, 64x64 each
    const int l15 = lane & 15, l4 = lane >> 4;

    const int bid = blockIdx.x;
    const int swz = (bid & 7) * (NWG / 8) + (bid >> 3);
    const int m0 = (swz / NX) * 128, n0 = (swz % NX) * 128;

    const int srow  = lane >> 2;
    const int sslot = lane & 3;

    f32x4 acc[4][4] = {};

    #define GSTAGE(buf, kt) do {                                                     \
        _Pragma("unroll")                                                            \
        for (int i = 0; i < 2; ++i) {                                                \
            int rbase = i * 64 + wave * 16;                                          \
            int row = rbase + srow;                                                  \
            gload_lds16(A  + (size_t)(m0 + row) * K + (kt) + sslot * 8, &As[(buf) * 4096 + rbase * 32]); \
            gload_lds16(Bt + (size_t)(n0 + row) * K + (kt) + sslot * 8, &Bs[(buf) * 4096 + rbase * 32]); \
        }                                                                            \
    } while (0)

    GSTAGE(0, 0);
    GSTAGE(1, 32);

    int cur = 0;
    for (int t = 0; t < 24; ++t) {
        if (t < 23) asm volatile("s_waitcnt vmcnt(4)" ::: "memory");
        else        asm volatile("s_waitcnt vmcnt(0)" ::: "memory");
        __builtin_amdgcn_s_barrier();
        if (t < 22) {
            int nb = cur + 2; if (nb >= 3) nb -= 3;
            GSTAGE(nb, (t + 2) * 32);
        }
        half8 af[4], bf[4];
        #pragma unroll
        for (int mi = 0; mi < 4; mi++) af[mi] = *(const half8*)&As[cur*4096 + (wm*64 + mi*16 + l15) * 32 + l4*8];
        #pragma unroll
        for (int ni = 0; ni < 4; ni++) bf[ni] = *(const half8*)&Bs[cur*4096 + (wn*64 + ni*16 + l15) * 32 + l4*8];
        #pragma unroll
        for (int mi = 0; mi < 4; mi++)
            #pragma unroll
            for (int ni = 0; ni < 4; ni++)
                acc[mi][ni] = MFMA16(af[mi], bf[ni], acc[mi][ni]);
        if (++cur >= 3) cur = 0;
    }
    #undef GSTAGE

    if (MODE == 0) {
        __syncthreads();
        f16* sC = (f16*)smem;          // [128][136]
        const int t3 = n0 / 768;
        const int bb = m0 >> 10;
        const int mo = m0 & 1023;
        const int h0 = (n0 - t3 * 768) >> 6;

        if (t3 < 2) {
            #pragma unroll
            for (int mi = 0; mi < 4; mi++)
                #pragma unroll
                for (int ni = 0; ni < 4; ni++)
                    #pragma unroll
                    for (int r = 0; r < 4; r++) {
                        int row = wm*64 + mi*16 + l4*4 + r;
                        int col = wn*64 + ni*16 + l15;
                        sC[row * 136 + col] = (f16)acc[mi][ni][r];
                    }
            __syncthreads();
            f16* outb = (t3 == 0) ? qbuf : kbuf;
            #pragma unroll
            for (int hc = 0; hc < 2; hc++) {
                f16* base = outb + ((size_t)(bb * 12 + h0 + hc) * 1024 + mo) * 64;
                #pragma unroll
                for (int i = 0; i < 4; i++) {
                    int row = wave * 32 + i * 8 + (lane >> 3);
                    int cc  = (lane & 7) * 8;
                    half8 v = *(const half8*)&sC[row * 136 + hc * 64 + cc];
                    *(half8*)(base + row * 64 + cc) = v;
                }
            }
        } else {
            #pragma unroll
            for (int mi = 0; mi < 4; mi++)
                #pragma unroll
                for (int ni = 0; ni < 4; ni++) {
                    int row0 = wm*64 + mi*16 + l4*4;
                    int col  = wn*64 + ni*16 + l15;
                    half4v pk;
                    #pragma unroll
                    for (int r = 0; r < 4; r++) pk[r] = (f16)acc[mi][ni][r];
                    *(half4v*)&sC[col * 136 + row0] = pk;
                }
            __syncthreads();
            #pragma unroll
            for (int i = 0; i < 8; i++) {
                int col = wave * 32 + i * 4 + (lane >> 4);
                int rc  = (lane & 15) * 8;
                half8 v = *(const half8*)&sC[col * 136 + rc];
                int head = h0 + (col >> 6), dd = col & 63;
                *(half8*)(vtbuf + ((size_t)(bb * 12 + head) * 64 + dd) * 1024 + mo + rc) = v;
            }
        }
    } else {
        #pragma unroll
        for (int mi = 0; mi < 4; mi++)
            #pragma unroll
            for (int ni = 0; ni < 4; ni++)
                #pragma unroll
                for (int r = 0; r < 4; r++) {
                    int gm = m0 + wm*64 + mi*16 + l4*4 + r;
                    int gn = n0 + wn*64 + ni*16 + l15;
                    out[(size_t)gm * 768 + gn] = acc[mi][ni][r] + bias[gn];
                }
    }
}

// ---------------- flash attention: 2-wave blocks (64 q), 5 blocks/CU, 32x32 MFMA ----------------
// grid (96 bh, 16 qblk): all q-blocks of a head land on one XCD (96%8==0) -> K/V L2-resident.
__global__ __launch_bounds__(128, 2)
void attn_kernel(const f16* __restrict__ qbuf, const f16* __restrict__ kbuf,
                 const f16* __restrict__ vtbuf, f16* __restrict__ obuf)
{
    __shared__ __align__(16) f16 Ks[2][4096];   // [buf][64 keys][64 d], XOR-swizzled content
    __shared__ __align__(16) f16 Vs[2][4096];   // [buf][64 d][64 keys], XOR-swizzled content
    const int tid = threadIdx.x;
    const int lane = tid & 63, wave = tid >> 6;   // 2 waves
    const int bh = blockIdx.x;              // 0..95
    const int b = bh / 12, h = bh % 12;
    const int q0 = blockIdx.y * 64 + wave * 32;
    const int l31 = lane & 31, hi = lane >> 5;
    const int sw0 = (l31 & 7) << 4;

    const f16* Q  = qbuf  + (size_t)bh * 65536;
    const f16* Kp = kbuf  + (size_t)bh * 65536;
    const f16* Vt = vtbuf + (size_t)bh * 65536;

    // Q fragments (B-operand of swapped QK, 32x32x16): col=l31, k=hi*8+j per 16-chunk
    const f16 slh = (f16)(0.125f * 1.44269504089f);
    half8 aq[4];
    #pragma unroll
    for (int c = 0; c < 4; c++) {
        aq[c] = *(const half8*)&Q[(size_t)(q0 + l31) * 64 + c * 16 + hi * 8];
        #pragma unroll
        for (int j = 0; j < 8; j++) aq[c][j] *= slh;
    }

    // staging geometry (pre-swizzled source, linear LDS dest); 128 threads stage 8KB K + 8KB V
    const int srow8 = lane >> 3;
    const int c16   = (lane & 7) ^ srow8;

    f32x16 o0 = {}, o1 = {};
    float lrq = 0.f, mrq = 0.f;

    #define STAGE(buf, kv) do {                                                     \
        _Pragma("unroll")                                                           \
        for (int i = 0; i < 4; ++i) {                                               \
            int rbase = wave * 32 + i * 8;                                          \
            int rl = rbase + srow8;                                                 \
            gload_lds16(Kp + (size_t)((kv) + rl) * 64 + c16 * 8, &Ks[buf][rbase * 64]); \
            gload_lds16(Vt + (size_t)rl * 1024 + (kv) + c16 * 8, &Vs[buf][rbase * 64]); \
        }                                                                           \
    } while (0)

    STAGE(0, 0);
    __syncthreads();

    for (int t = 0; t < 16; ++t) {
        const int cur = t & 1;
        if (t < 15) STAGE(cur ^ 1, (t + 1) * 64);

        const char* Kb = (const char*)&Ks[cur][0];
        const char* Vb = (const char*)&Vs[cur][0];

        // swapped QK (32x32x16): st = S^T[key][q] - mrq, log2 domain
        f32x16 st0, st1;
        #pragma unroll
        for (int j = 0; j < 16; j++) { st0[j] = -mrq; st1[j] = -mrq; }
        __builtin_amdgcn_s_setprio(1);
        #pragma unroll
        for (int c = 0; c < 4; c++) {
            int koff = (c * 32 + hi * 16) ^ sw0;
            half8 k0 = *(const half8*)(Kb + l31 * 128 + koff);
            half8 k1 = *(const half8*)(Kb + (32 + l31) * 128 + koff);
            st0 = MFMA32(k0, aq[c], st0);
            st1 = MFMA32(k1, aq[c], st1);
        }
        __builtin_amdgcn_s_setprio(0);

        // row max: depth-5 balanced tree, named scalars
        float m16;
        {
            float p0 = fmaxf(fmaxf(st0[0],  st0[1]),  fmaxf(st0[2],  st0[3]));
            float p1 = fmaxf(fmaxf(st0[4],  st0[5]),  fmaxf(st0[6],  st0[7]));
            float p2 = fmaxf(fmaxf(st0[8],  st0[9]),  fmaxf(st0[10], st0[11]));
            float p3 = fmaxf(fmaxf(st0[12], st0[13]), fmaxf(st0[14], st0[15]));
            float r0 = fmaxf(fmaxf(st1[0],  st1[1]),  fmaxf(st1[2],  st1[3]));
            float r1 = fmaxf(fmaxf(st1[4],  st1[5]),  fmaxf(st1[6],  st1[7]));
            float r2 = fmaxf(fmaxf(st1[8],  st1[9]),  fmaxf(st1[10], st1[11]));
            float r3 = fmaxf(fmaxf(st1[12], st1[13]), fmaxf(st1[14], st1[15]));
            m16 = fmaxf(fmaxf(fmaxf(p0, p1), fmaxf(p2, p3)),
                        fmaxf(fmaxf(r0, r1), fmaxf(r2, r3)));
        }
        m16 = fmaxf(m16, xswap32(m16, hi));

        // defer-max (T13)
        if (!__all(m16 <= 11.0f)) {
            float d = fmaxf(m16, 0.f);
            float alpha = exp2f(-d);
            mrq += d;
            #pragma unroll
            for (int j = 0; j < 16; j++) { st0[j] -= d; st1[j] -= d; }
            lrq *= alpha;
            #pragma unroll
            for (int reg = 0; reg < 16; reg++) {
                float a = __shfl(alpha, (reg & 3) + 8 * (reg >> 2) + 4 * hi);
                o0[reg] *= a; o1[reg] *= a;
            }
        }

        // P = exp2(st): one exp2 per entry, <=4 live scalars per group;
        // pack -> permlane32_swap -> PV A-fragments (in registers).
        float rs = 0.f;
        half8 pa[4];
        #pragma unroll
        for (int tile = 0; tile < 2; tile++) {
            const f32x16& sv = tile ? st1 : st0;
            #pragma unroll
            for (int half16 = 0; half16 < 2; half16++) {
                int rb = half16 * 8;
                unsigned A1, B1, A2, B2;
                {
                    float e0 = exp2f(sv[rb+0]), e1 = exp2f(sv[rb+1]);
                    float e4 = exp2f(sv[rb+4]), e5 = exp2f(sv[rb+5]);
                    rs += (e0 + e1) + (e4 + e5);
                    A1 = pk2(e0, e1); B1 = pk2(e4, e5);
                    plswap(A1, B1);
                }
                {
                    float e2 = exp2f(sv[rb+2]), e3 = exp2f(sv[rb+3]);
                    float e6 = exp2f(sv[rb+6]), e7 = exp2f(sv[rb+7]);
                    rs += (e2 + e3) + (e6 + e7);
                    A2 = pk2(e2, e3); B2 = pk2(e6, e7);
                    plswap(A2, B2);
                }
                uint4v w = {A1, A2, B1, B2};
                pa[tile * 2 + half16] = __builtin_bit_cast(half8, w);
            }
        }
        rs += xswap32(rs, hi);
        lrq += rs;

        // PV (32x32x16): A = pa (registers), B = V^T frags from LDS
        __builtin_amdgcn_s_setprio(1);
        #pragma unroll
        for (int kc = 0; kc < 4; kc++) {
            int koff = (kc * 32 + hi * 16) ^ sw0;
            half8 v0 = *(const half8*)(Vb + l31 * 128 + koff);
            half8 v1 = *(const half8*)(Vb + (32 + l31) * 128 + koff);
            o0 = MFMA32(pa[kc], v0, o0);
            o1 = MFMA32(pa[kc], v1, o1);
        }
        __builtin_amdgcn_s_setprio(0);

        __syncthreads();   // drains vmcnt (staged tile ready) + guards buffer reuse
    }
    #undef STAGE

    // epilogue: redistribute 1/lrq (at q=l31) to O's reg-mapped rows
    float rq = 1.0f / lrq;
    f16* Op = obuf + (size_t)b * 1024 * 768 + h * 64;
    #pragma unroll
    for (int reg = 0; reg < 16; reg++) {
        int qrow = (reg & 3) + 8 * (reg >> 2) + 4 * hi;
        float inv = __shfl(rq, qrow);
        size_t base = (size_t)(q0 + qrow) * 768;
        Op[base + l31]      = (f16)(o0[reg] * inv);
        Op[base + 32 + l31] = (f16)(o1[reg] * inv);
    }
}

extern "C" void kernel_launch(void* const* d_in, const int* in_sizes, int n_in,
                              void* d_out, int out_size, void* d_ws, size_t ws_size,
                              hipStream_t stream) {
    const float* x      = (const float*)d_in[0];
    const float* w_qkv  = (const float*)d_in[1];
    const float* w_proj = (const float*)d_in[2];
    const float* b_proj = (const float*)d_in[3];
    float* out = (float*)d_out;
    char* ws = (char*)d_ws;

    f16* x_h      = (f16*)(ws + 0);
    f16* w_qkv_t  = (f16*)(ws + 12582912);
    f16* w_proj_t = (f16*)(ws + 16121856);
    f16* qb       = (f16*)(ws + 17301504);
    f16* kb       = (f16*)(ws + 29884416);
    f16* vtb      = (f16*)(ws + 42467328);
    f16* ob       = (f16*)(ws + 55050240);

    cast_f32_to_f16<<<dim3(6144), dim3(256), 0, stream>>>(x, x_h, 6291456 / 4);
    transpose_cast<<<dim3(2304 / 32, 768 / 32), dim3(256), 0, stream>>>(w_qkv, w_qkv_t, 768, 2304);
    transpose_cast<<<dim3(768 / 32, 768 / 32), dim3(256), 0, stream>>>(w_proj, w_proj_t, 768, 768);
    gemm_bt<0><<<dim3(18 * 64), dim3(256), 0, stream>>>(
        x_h, w_qkv_t, qb, kb, vtb, nullptr, nullptr);
    attn_kernel<<<dim3(96, 16), dim3(128), 0, stream>>>(qb, kb, vtb, ob);
    gemm_bt<1><<<dim3(6 * 64), dim3(256), 0, stream>>>(
        ob, w_proj_t, nullptr, nullptr, nullptr, out, b_proj);
}

// Round 16
// 121.074 us; speedup vs baseline: 2.0798x; 1.2930x over previous
//
#include <hip/hip_runtime.h>

typedef _Float16 f16;
typedef _Float16 half8 __attribute__((ext_vector_type(8)));
typedef _Float16 half4v __attribute__((ext_vector_type(4)));
typedef __fp16 fp16x2 __attribute__((ext_vector_type(2)));
typedef float f32x4 __attribute__((ext_vector_type(4)));
typedef float f32x16 __attribute__((ext_vector_type(16)));
typedef unsigned uint4v __attribute__((ext_vector_type(4)));

#define MFMA16(a,b,c) __builtin_amdgcn_mfma_f32_16x16x32_f16((a),(b),(c),0,0,0)
#define MFMA32(a,b,c) __builtin_amdgcn_mfma_f32_32x32x16_f16((a),(b),(c),0,0,0)

__device__ __forceinline__ void gload_lds16(const f16* g, f16* l) {
    __builtin_amdgcn_global_load_lds(
        (const __attribute__((address_space(1))) unsigned int*)g,
        (__attribute__((address_space(3))) unsigned int*)l, 16, 0, 0);
}

__device__ __forceinline__ void plswap(unsigned &a, unsigned &b) {
    asm volatile("v_permlane32_swap_b32 %0, %1" : "+v"(a), "+v"(b));
}

__device__ __forceinline__ unsigned pk2(float a, float b) {
    return __builtin_bit_cast(unsigned, __builtin_amdgcn_cvt_pkrtz(a, b));
}

// raw v_exp_f32 (exp2f without -ffast-math lowers to a guarded libm sequence)
__device__ __forceinline__ float fexp2(float x) {
#if __has_builtin(__builtin_amdgcn_exp2f)
    return __builtin_amdgcn_exp2f(x);
#else
    return exp2f(x);
#endif
}

// lane <-> lane^32 exchange via full-rate permlane (not ds_bpermute)
__device__ __forceinline__ float xswap32(float x, int hi) {
    unsigned a = __builtin_bit_cast(unsigned, x), b = a;
    asm volatile("v_permlane32_swap_b32 %0, %1" : "+v"(a), "+v"(b));
    return __builtin_bit_cast(float, hi ? a : b);
}

// ---------------- cast fp32 -> fp16 (vectorized) ----------------
__global__ void cast_f32_to_f16(const float* __restrict__ in, f16* __restrict__ out, int n4) {
    int i = blockIdx.x * blockDim.x + threadIdx.x;
    if (i < n4) {
        float4 v = ((const float4*)in)[i];
        half4v h;
        h.x = (f16)v.x; h.y = (f16)v.y; h.z = (f16)v.z; h.w = (f16)v.w;
        ((half4v*)out)[i] = h;
    }
}

// ---------------- transpose + cast: in[K][N] fp32 -> out[N][K] fp16 ----------------
__global__ void transpose_cast(const float* __restrict__ in, f16* __restrict__ out, int K, int N) {
    __shared__ f16 tile[32][33];
    int n0 = blockIdx.x * 32, k0 = blockIdx.y * 32;
    int tx = threadIdx.x & 31, ty = threadIdx.x >> 5;   // 256 threads = 32x8
    for (int r = ty; r < 32; r += 8)
        tile[r][tx] = (f16)in[(size_t)(k0 + r) * N + (n0 + tx)];
    __syncthreads();
    for (int r = ty; r < 32; r += 8)
        out[(size_t)(n0 + r) * K + (k0 + tx)] = tile[tx][r];
}

// ---------------- GEMM: C[M][N] = A[M][768] * Bt[N][768]^T ----------------
template<int MODE>
__global__ __launch_bounds__(256, 3)
void gemm_bt(const f16* __restrict__ A, const f16* __restrict__ Bt,
             f16* __restrict__ qbuf, f16* __restrict__ kbuf, f16* __restrict__ vtbuf,
             float* __restrict__ out, const float* __restrict__ bias)
{
    constexpr int K = 768;
    constexpr int NX = (MODE == 0) ? 18 : 6;   // n-tiles
    constexpr int NWG = NX * 64;
    __shared__ __align__(16) char smem[49152];
    f16* As = (f16*)smem;              // [3][128*32]
    f16* Bs = (f16*)(smem + 24576);    // [3][128*32]
    const int tid  = threadIdx.x;
    const int lane = tid & 63, wave = tid >> 6;
    const int wm = wave >> 1, wn = wave & 1;          // 2x2 waves, 64x64 each
    const int l15 = lane & 15, l4 = lane >> 4;

    const int bid = blockIdx.x;
    const int swz = (bid & 7) * (NWG / 8) + (bid >> 3);
    const int m0 = (swz / NX) * 128, n0 = (swz % NX) * 128;

    const int srow  = lane >> 2;
    const int sslot = lane & 3;

    f32x4 acc[4][4] = {};

    #define GSTAGE(buf, kt) do {                                                     \
        _Pragma("unroll")                                                            \
        for (int i = 0; i < 2; ++i) {                                                \
            int rbase = i * 64 + wave * 16;                                          \
            int row = rbase + srow;                                                  \
            gload_lds16(A  + (size_t)(m0 + row) * K + (kt) + sslot * 8, &As[(buf) * 4096 + rbase * 32]); \
            gload_lds16(Bt + (size_t)(n0 + row) * K + (kt) + sslot * 8, &Bs[(buf) * 4096 + rbase * 32]); \
        }                                                                            \
    } while (0)

    GSTAGE(0, 0);
    GSTAGE(1, 32);

    int cur = 0;
    for (int t = 0; t < 24; ++t) {
        if (t < 23) asm volatile("s_waitcnt vmcnt(4)" ::: "memory");
        else        asm volatile("s_waitcnt vmcnt(0)" ::: "memory");
        __builtin_amdgcn_s_barrier();
        if (t < 22) {
            int nb = cur + 2; if (nb >= 3) nb -= 3;
            GSTAGE(nb, (t + 2) * 32);
        }
        half8 af[4], bf[4];
        #pragma unroll
        for (int mi = 0; mi < 4; mi++) af[mi] = *(const half8*)&As[cur*4096 + (wm*64 + mi*16 + l15) * 32 + l4*8];
        #pragma unroll
        for (int ni = 0; ni < 4; ni++) bf[ni] = *(const half8*)&Bs[cur*4096 + (wn*64 + ni*16 + l15) * 32 + l4*8];
        #pragma unroll
        for (int mi = 0; mi < 4; mi++)
            #pragma unroll
            for (int ni = 0; ni < 4; ni++)
                acc[mi][ni] = MFMA16(af[mi], bf[ni], acc[mi][ni]);
        if (++cur >= 3) cur = 0;
    }
    #undef GSTAGE

    if (MODE == 0) {
        __syncthreads();
        f16* sC = (f16*)smem;          // [128][136]
        const int t3 = n0 / 768;
        const int bb = m0 >> 10;
        const int mo = m0 & 1023;
        const int h0 = (n0 - t3 * 768) >> 6;

        if (t3 < 2) {
            #pragma unroll
            for (int mi = 0; mi < 4; mi++)
                #pragma unroll
                for (int ni = 0; ni < 4; ni++)
                    #pragma unroll
                    for (int r = 0; r < 4; r++) {
                        int row = wm*64 + mi*16 + l4*4 + r;
                        int col = wn*64 + ni*16 + l15;
                        sC[row * 136 + col] = (f16)acc[mi][ni][r];
                    }
            __syncthreads();
            f16* outb = (t3 == 0) ? qbuf : kbuf;
            #pragma unroll
            for (int hc = 0; hc < 2; hc++) {
                f16* base = outb + ((size_t)(bb * 12 + h0 + hc) * 1024 + mo) * 64;
                #pragma unroll
                for (int i = 0; i < 4; i++) {
                    int row = wave * 32 + i * 8 + (lane >> 3);
                    int cc  = (lane & 7) * 8;
                    half8 v = *(const half8*)&sC[row * 136 + hc * 64 + cc];
                    *(half8*)(base + row * 64 + cc) = v;
                }
            }
        } else {
            #pragma unroll
            for (int mi = 0; mi < 4; mi++)
                #pragma unroll
                for (int ni = 0; ni < 4; ni++) {
                    int row0 = wm*64 + mi*16 + l4*4;
                    int col  = wn*64 + ni*16 + l15;
                    half4v pk;
                    #pragma unroll
                    for (int r = 0; r < 4; r++) pk[r] = (f16)acc[mi][ni][r];
                    *(half4v*)&sC[col * 136 + row0] = pk;
                }
            __syncthreads();
            #pragma unroll
            for (int i = 0; i < 8; i++) {
                int col = wave * 32 + i * 4 + (lane >> 4);
                int rc  = (lane & 15) * 8;
                half8 v = *(const half8*)&sC[col * 136 + rc];
                int head = h0 + (col >> 6), dd = col & 63;
                *(half8*)(vtbuf + ((size_t)(bb * 12 + head) * 64 + dd) * 1024 + mo + rc) = v;
            }
        }
    } else {
        #pragma unroll
        for (int mi = 0; mi < 4; mi++)
            #pragma unroll
            for (int ni = 0; ni < 4; ni++)
                #pragma unroll
                for (int r = 0; r < 4; r++) {
                    int gm = m0 + wm*64 + mi*16 + l4*4 + r;
                    int gn = n0 + wn*64 + ni*16 + l15;
                    out[(size_t)gm * 768 + gn] = acc[mi][ni][r] + bias[gn];
                }
    }
}

// ---------------- flash attention: 3-buffer QK-ahead pipeline, native exp, 32x32 MFMA ----------------
// grid (96 bh, 8 qblk), 256 threads; 48KB LDS -> 3 blocks/CU (= grid supply).
__global__ __launch_bounds__(256, 3)
void attn_kernel(const f16* __restrict__ qbuf, const f16* __restrict__ kbuf,
                 const f16* __restrict__ vtbuf, f16* __restrict__ obuf)
{
    __shared__ __align__(16) f16 Ks[3][4096];   // [buf][64 keys][64 d], XOR-swizzled content
    __shared__ __align__(16) f16 Vs[3][4096];   // [buf][64 d][64 keys], XOR-swizzled content
    const int tid = threadIdx.x;
    const int lane = tid & 63, wave = tid >> 6;
    const int bh = blockIdx.x;              // 0..95
    const int b = bh / 12, h = bh % 12;
    const int q0 = blockIdx.y * 128 + wave * 32;
    const int l31 = lane & 31, hi = lane >> 5;
    const int sw0 = (l31 & 7) << 4;

    const f16* Q  = qbuf  + (size_t)bh * 65536;
    const f16* Kp = kbuf  + (size_t)bh * 65536;
    const f16* Vt = vtbuf + (size_t)bh * 65536;

    // Q fragments (B-operand of swapped QK, 32x32x16)
    const f16 slh = (f16)(0.125f * 1.44269504089f);
    half8 aq[4];
    #pragma unroll
    for (int c = 0; c < 4; c++) {
        aq[c] = *(const half8*)&Q[(size_t)(q0 + l31) * 64 + c * 16 + hi * 8];
        #pragma unroll
        for (int j = 0; j < 8; j++) aq[c][j] *= slh;
    }

    const int srow8 = lane >> 3;
    const int c16   = (lane & 7) ^ srow8;

    f32x16 o0 = {}, o1 = {};
    float lrq = 0.f, mrq = 0.f, stale = 0.f;

    #define STAGE(buf, kv) do {                                                     \
        _Pragma("unroll")                                                           \
        for (int i = 0; i < 2; ++i) {                                               \
            int rbase = wave * 16 + i * 8;                                          \
            int rl = rbase + srow8;                                                 \
            gload_lds16(Kp + (size_t)((kv) + rl) * 64 + c16 * 8, &Ks[buf][rbase * 64]); \
            gload_lds16(Vt + (size_t)rl * 1024 + (kv) + c16 * 8, &Vs[buf][rbase * 64]); \
        }                                                                           \
    } while (0)

    #define QKISSUE(dst0, dst1, kb, minit) do {                                     \
        _Pragma("unroll")                                                           \
        for (int j = 0; j < 16; j++) { dst0[j] = (minit); dst1[j] = (minit); }      \
        __builtin_amdgcn_s_setprio(1);                                              \
        _Pragma("unroll")                                                           \
        for (int c = 0; c < 4; c++) {                                               \
            int koff = (c * 32 + hi * 16) ^ sw0;                                    \
            half8 k0 = *(const half8*)((kb) + l31 * 128 + koff);                    \
            half8 k1 = *(const half8*)((kb) + (32 + l31) * 128 + koff);             \
            dst0 = MFMA32(k0, aq[c], dst0);                                         \
            dst1 = MFMA32(k1, aq[c], dst1);                                         \
        }                                                                           \
        __builtin_amdgcn_s_setprio(0);                                              \
    } while (0)

    STAGE(0, 0);
    STAGE(1, 64);
    __syncthreads();                 // both tiles staged (vmcnt drained by barrier)

    f32x16 st0, st1;
    QKISSUE(st0, st1, (const char*)&Ks[0][0], 0.f);   // tile 0, mrq = 0

    int bcur = 0;
    for (int t = 0; t < 16; ++t) {
        int bn1 = bcur + 1; if (bn1 >= 3) bn1 -= 3;
        int bn2 = bcur + 2; if (bn2 >= 3) bn2 -= 3;

        if (t < 14) STAGE(bn2, (t + 2) * 64);

        // issue QK(t+1) early: drains on the MFMA pipe while softmax(t) runs on VALU
        f32x16 sN0, sN1;
        if (t < 15) QKISSUE(sN0, sN1, (const char*)&Ks[bn1][0], -mrq);

        // ---- softmax(t) on st0/st1 ----
        if (__any(stale != 0.f)) {      // align in-flight-issued st to current mrq (rare)
            #pragma unroll
            for (int j = 0; j < 16; j++) { st0[j] -= stale; st1[j] -= stale; }
        }
        stale = 0.f;

        float m16;
        {
            float p0 = fmaxf(fmaxf(st0[0],  st0[1]),  fmaxf(st0[2],  st0[3]));
            float p1 = fmaxf(fmaxf(st0[4],  st0[5]),  fmaxf(st0[6],  st0[7]));
            float p2 = fmaxf(fmaxf(st0[8],  st0[9]),  fmaxf(st0[10], st0[11]));
            float p3 = fmaxf(fmaxf(st0[12], st0[13]), fmaxf(st0[14], st0[15]));
            float r0 = fmaxf(fmaxf(st1[0],  st1[1]),  fmaxf(st1[2],  st1[3]));
            float r1 = fmaxf(fmaxf(st1[4],  st1[5]),  fmaxf(st1[6],  st1[7]));
            float r2 = fmaxf(fmaxf(st1[8],  st1[9]),  fmaxf(st1[10], st1[11]));
            float r3 = fmaxf(fmaxf(st1[12], st1[13]), fmaxf(st1[14], st1[15]));
            m16 = fmaxf(fmaxf(fmaxf(p0, p1), fmaxf(p2, p3)),
                        fmaxf(fmaxf(r0, r1), fmaxf(r2, r3)));
        }
        m16 = fmaxf(m16, xswap32(m16, hi));

        if (!__all(m16 <= 11.0f)) {     // defer-max (T13)
            float d = fmaxf(m16, 0.f);
            float alpha = fexp2(-d);
            mrq += d;
            stale = d;                   // QK(t+1) was issued with old mrq
            #pragma unroll
            for (int j = 0; j < 16; j++) { st0[j] -= d; st1[j] -= d; }
            lrq *= alpha;
            #pragma unroll
            for (int reg = 0; reg < 16; reg++) {
                float a = __shfl(alpha, (reg & 3) + 8 * (reg >> 2) + 4 * hi);
                o0[reg] *= a; o1[reg] *= a;
            }
        }

        // P = exp2(st): one raw v_exp per entry; pack -> permlane32_swap -> PV A-frags
        float rs = 0.f;
        half8 pa[4];
        #pragma unroll
        for (int tile = 0; tile < 2; tile++) {
            const f32x16& sv = tile ? st1 : st0;
            #pragma unroll
            for (int half16 = 0; half16 < 2; half16++) {
                int rb = half16 * 8;
                unsigned A1, B1, A2, B2;
                {
                    float e0 = fexp2(sv[rb+0]), e1 = fexp2(sv[rb+1]);
                    float e4 = fexp2(sv[rb+4]), e5 = fexp2(sv[rb+5]);
                    rs += (e0 + e1) + (e4 + e5);
                    A1 = pk2(e0, e1); B1 = pk2(e4, e5);
                    plswap(A1, B1);
                }
                {
                    float e2 = fexp2(sv[rb+2]), e3 = fexp2(sv[rb+3]);
                    float e6 = fexp2(sv[rb+6]), e7 = fexp2(sv[rb+7]);
                    rs += (e2 + e3) + (e6 + e7);
                    A2 = pk2(e2, e3); B2 = pk2(e6, e7);
                    plswap(A2, B2);
                }
                uint4v w = {A1, A2, B1, B2};
                pa[tile * 2 + half16] = __builtin_bit_cast(half8, w);
            }
        }
        rs += xswap32(rs, hi);
        lrq += rs;

        // PV(t) from Vs[bcur]
        {
            const char* Vb = (const char*)&Vs[bcur][0];
            __builtin_amdgcn_s_setprio(1);
            #pragma unroll
            for (int kc = 0; kc < 4; kc++) {
                int koff = (kc * 32 + hi * 16) ^ sw0;
                half8 v0 = *(const half8*)(Vb + l31 * 128 + koff);
                half8 v1 = *(const half8*)(Vb + (32 + l31) * 128 + koff);
                o0 = MFMA32(pa[kc], v0, o0);
                o1 = MFMA32(pa[kc], v1, o1);
            }
            __builtin_amdgcn_s_setprio(0);
        }

        if (t < 15) {
            // STAGE(t+2) must be visible before QK(t+2) next iter; buffer recycle safe after barrier
            asm volatile("s_waitcnt vmcnt(0)" ::: "memory");
            __builtin_amdgcn_s_barrier();
            st0 = sN0; st1 = sN1;
        }
        bcur = bn1;
    }
    #undef QKISSUE
    #undef STAGE

    // epilogue: redistribute 1/lrq (at q=l31) to O's reg-mapped rows
    float rq = 1.0f / lrq;
    f16* Op = obuf + (size_t)b * 1024 * 768 + h * 64;
    #pragma unroll
    for (int reg = 0; reg < 16; reg++) {
        int qrow = (reg & 3) + 8 * (reg >> 2) + 4 * hi;
        float inv = __shfl(rq, qrow);
        size_t base = (size_t)(q0 + qrow) * 768;
        Op[base + l31]      = (f16)(o0[reg] * inv);
        Op[base + 32 + l31] = (f16)(o1[reg] * inv);
    }
}

extern "C" void kernel_launch(void* const* d_in, const int* in_sizes, int n_in,
                              void* d_out, int out_size, void* d_ws, size_t ws_size,
                              hipStream_t stream) {
    const float* x      = (const float*)d_in[0];
    const float* w_qkv  = (const float*)d_in[1];
    const float* w_proj = (const float*)d_in[2];
    const float* b_proj = (const float*)d_in[3];
    float* out = (float*)d_out;
    char* ws = (char*)d_ws;

    f16* x_h      = (f16*)(ws + 0);
    f16* w_qkv_t  = (f16*)(ws + 12582912);
    f16* w_proj_t = (f16*)(ws + 16121856);
    f16* qb       = (f16*)(ws + 17301504);
    f16* kb       = (f16*)(ws + 29884416);
    f16* vtb      = (f16*)(ws + 42467328);
    f16* ob       = (f16*)(ws + 55050240);

    cast_f32_to_f16<<<dim3(6144), dim3(256), 0, stream>>>(x, x_h, 6291456 / 4);
    transpose_cast<<<dim3(2304 / 32, 768 / 32), dim3(256), 0, stream>>>(w_qkv, w_qkv_t, 768, 2304);
    transpose_cast<<<dim3(768 / 32, 768 / 32), dim3(256), 0, stream>>>(w_proj, w_proj_t, 768, 768);
    gemm_bt<0><<<dim3(18 * 64), dim3(256), 0, stream>>>(
        x_h, w_qkv_t, qb, kb, vtb, nullptr, nullptr);
    attn_kernel<<<dim3(96, 8), dim3(256), 0, stream>>>(qb, kb, vtb, ob);
    gemm_bt<1><<<dim3(6 * 64), dim3(256), 0, stream>>>(
        ob, w_proj_t, nullptr, nullptr, nullptr, out, b_proj);
}